// Round 10
// baseline (234.117 us; speedup 1.0000x reference)
//
#include <hip/hip_runtime.h>
#include <math.h>

#define D_DIM 256
#define HW 16384
#define C 19
#define EPS 1e-8f

#define S_SC 1048576.0f        // 2^20 fixed point, |class sum| < ~2000 -> int32-safe
#define IS_S (1.0f/1048576.0f)
#define U_SC 16777216.0f       // 2^24 fixed point, |unit sum| < ~100
#define IS_U (1.0f/16777216.0f)

// ws layout (4-byte words) — everything plain-stored, NO zeroing kernel needed
#define OFF_S      0           // int[4864]    final S
#define OFF_U      4864        // int[4864]    final U
#define OFF_PCNT   9728        // int[64][19]  count partials
#define OFF_IO     10944       // float[131072] U_SC/||f_px||
#define OFF_PNF    142016      // float[2048][2080] nf slab-partials (stride non-pow2)
#define PNF_STRIDE 2080
#define OFF_PS     4401856     // int[2048][152] S partial rows
#define OFF_PU     4713152     // int[2048][152] U partial rows

// block id mapping for kA/kB: bid = (b<<8) | (slab<<3) | oct
//   b<8 image, slab<32 (8 d's), oct<8 (2048 hw)

// ---------- kA: sweep 1 — nf partials + S partials + counts ----------
// grid 2048, 256 thr; thread t owns hw = oct*2048 + t*4 + it*1024 (it<2), 8 d's.
__global__ __launch_bounds__(256) void kA_stream(const float* __restrict__ in,
                                                 const int* __restrict__ tgt,
                                                 int* __restrict__ wsi) {
    __shared__ int sS[8 * 161];   // 8 copies: bank (copy + 20d + l) % 32
    __shared__ int sH[8 * 21];
    const int tid = threadIdx.x;
    const int bid = blockIdx.x;
    const int b = bid >> 8, slab = (bid >> 3) & 31, oct = bid & 7;
    const int copy = tid & 7;
    for (int i = tid; i < 8 * 161; i += 256) sS[i] = 0;
    if (tid < 8 * 21) sH[tid] = 0;
    __syncthreads();

    const int hwb = (oct << 11) + (tid << 2);
    const int pb  = (b << 14) + hwb;
    int4 lab[2];
    #pragma unroll
    for (int it = 0; it < 2; ++it) lab[it] = *(const int4*)(tgt + pb + (it << 10));

    const float* base = in + (((size_t)((b << 8) + (slab << 3))) << 14) + hwb;
    float4 nf[2];
    nf[0] = make_float4(0.f, 0.f, 0.f, 0.f);
    nf[1] = make_float4(0.f, 0.f, 0.f, 0.f);

    #pragma unroll
    for (int d = 0; d < 8; ++d) {
        float4 v[2];
        #pragma unroll
        for (int it = 0; it < 2; ++it)
            v[it] = *(const float4*)(base + ((size_t)d << 14) + (it << 10));
        const int sb = copy * 161 + d * 20;
        #pragma unroll
        for (int it = 0; it < 2; ++it) {
            nf[it].x += v[it].x * v[it].x; nf[it].y += v[it].y * v[it].y;
            nf[it].z += v[it].z * v[it].z; nf[it].w += v[it].w * v[it].w;
            atomicAdd(&sS[sb + lab[it].x], __float2int_rn(v[it].x * S_SC));
            atomicAdd(&sS[sb + lab[it].y], __float2int_rn(v[it].y * S_SC));
            atomicAdd(&sS[sb + lab[it].z], __float2int_rn(v[it].z * S_SC));
            atomicAdd(&sS[sb + lab[it].w], __float2int_rn(v[it].w * S_SC));
        }
    }

    {   // nf slab-partial writeout (coalesced float4, non-pow2 row stride)
        float* pnf = (float*)wsi + OFF_PNF
                   + (size_t)(((b << 3) + oct) * 32 + slab) * PNF_STRIDE;
        *(float4*)(pnf + (tid << 2))        = nf[0];
        *(float4*)(pnf + 1024 + (tid << 2)) = nf[1];
    }

    if (slab == 0) {                           // counts: each px exactly once
        #pragma unroll
        for (int it = 0; it < 2; ++it) {
            atomicAdd(&sH[copy * 21 + lab[it].x], 1);
            atomicAdd(&sH[copy * 21 + lab[it].y], 1);
            atomicAdd(&sH[copy * 21 + lab[it].z], 1);
            atomicAdd(&sH[copy * 21 + lab[it].w], 1);
        }
    }
    __syncthreads();
    if (tid < 152) {                           // merge 8 copies -> S partial row
        const int d = tid / 19, l = tid - (tid / 19) * 19;
        int acc = 0;
        #pragma unroll
        for (int c = 0; c < 8; ++c) acc += sS[c * 161 + d * 20 + l];
        wsi[OFF_PS + bid * 152 + tid] = acc;
    }
    if (slab == 0 && tid < C) {
        int t = 0;
        #pragma unroll
        for (int c = 0; c < 8; ++c) t += sH[c * 21 + tid];
        wsi[OFF_PCNT + ((b << 3) + oct) * 19 + tid] = t;
    }
}

// ---------- kA2: io = U_SC * rsqrt(sum over 32 slab-partials) ----------
// grid 64 = (b<8) x (oct<8); 256 thr x 2 float4 = 2048 px.
__global__ __launch_bounds__(256) void kA2_io(int* __restrict__ wsi) {
    float* wsf = (float*)wsi;
    const int boct = blockIdx.x, tid = threadIdx.x;
    const float* pn0 = wsf + OFF_PNF + (size_t)(boct * 32) * PNF_STRIDE;
    #pragma unroll
    for (int it = 0; it < 2; ++it) {
        const int j = (it << 10) + (tid << 2);
        float4 acc = {0.f, 0.f, 0.f, 0.f};
        #pragma unroll 8
        for (int s = 0; s < 32; ++s) {
            float4 v = *(const float4*)(pn0 + (size_t)s * PNF_STRIDE + j);
            acc.x += v.x; acc.y += v.y; acc.z += v.z; acc.w += v.w;
        }
        float4 io;
        io.x = acc.x > 0.f ? U_SC * rsqrtf(acc.x) : 0.f;
        io.y = acc.y > 0.f ? U_SC * rsqrtf(acc.y) : 0.f;
        io.z = acc.z > 0.f ? U_SC * rsqrtf(acc.z) : 0.f;
        io.w = acc.w > 0.f ? U_SC * rsqrtf(acc.w) : 0.f;
        *(float4*)(wsf + OFF_IO + ((boct >> 3) << 14) + ((boct & 7) << 11) + j) = io;
    }
}

// ---------- kB: sweep 2 (L3-hot) — U partials ----------
__global__ __launch_bounds__(256) void kB_stream(const float* __restrict__ in,
                                                 const int* __restrict__ tgt,
                                                 int* __restrict__ wsi) {
    __shared__ int sU[8 * 161];
    const int tid = threadIdx.x;
    const int bid = blockIdx.x;
    const int b = bid >> 8, slab = (bid >> 3) & 31, oct = bid & 7;
    const int copy = tid & 7;
    for (int i = tid; i < 8 * 161; i += 256) sU[i] = 0;
    __syncthreads();

    const int hwb = (oct << 11) + (tid << 2);
    const int pb  = (b << 14) + hwb;
    const float* iof = (const float*)wsi + OFF_IO;
    int4   lab[2];
    float4 io4[2];
    #pragma unroll
    for (int it = 0; it < 2; ++it) {
        lab[it] = *(const int4*)(tgt + pb + (it << 10));
        io4[it] = *(const float4*)(iof + pb + (it << 10));
    }

    const float* base = in + (((size_t)((b << 8) + (slab << 3))) << 14) + hwb;
    #pragma unroll
    for (int d = 0; d < 8; ++d) {
        float4 v[2];
        #pragma unroll
        for (int it = 0; it < 2; ++it)
            v[it] = *(const float4*)(base + ((size_t)d << 14) + (it << 10));
        const int sb = copy * 161 + d * 20;
        #pragma unroll
        for (int it = 0; it < 2; ++it) {
            atomicAdd(&sU[sb + lab[it].x], __float2int_rn(v[it].x * io4[it].x));
            atomicAdd(&sU[sb + lab[it].y], __float2int_rn(v[it].y * io4[it].y));
            atomicAdd(&sU[sb + lab[it].z], __float2int_rn(v[it].z * io4[it].z));
            atomicAdd(&sU[sb + lab[it].w], __float2int_rn(v[it].w * io4[it].w));
        }
    }
    __syncthreads();
    if (tid < 152) {
        const int d = tid / 19, l = tid - (tid / 19) * 19;
        int acc = 0;
        #pragma unroll
        for (int c = 0; c < 8; ++c) acc += sU[c * 161 + d * 20 + l];
        wsi[OFF_PU + bid * 152 + tid] = acc;
    }
}

// ---------- kM: merge 64 (b,oct)-rows per slab -> final S/U, plain stores ----------
// grid 64: a = (S/U), ss = slab.
__global__ __launch_bounds__(256) void kM_merge(int* __restrict__ wsi) {
    const int a = blockIdx.x >> 5, ss = blockIdx.x & 31;
    const int tid = threadIdx.x;
    if (tid >= 152) return;
    const int* src = wsi + (a ? OFF_PU : OFF_PS);
    int acc = 0;
    #pragma unroll
    for (int r = 0; r < 64; ++r) {             // row = (b<<8) + (ss<<3) + oct
        const int row = ((r >> 3) << 8) + (ss << 3) + (r & 7);
        acc += src[row * 152 + tid];
    }
    const int d = tid / 19, l = tid - (tid / 19) * 19;
    wsi[(a ? OFF_U : OFF_S) + l * D_DIM + (ss << 3) + d] = acc;
}

// ---------- k2: centers, norms, Gram/diff, sim, final (1 block; validated) ----------
__global__ __launch_bounds__(512) void k2_final(const int* __restrict__ wsi,
                                                float* __restrict__ out) {
    __shared__ __align__(16) float s_cen[C * 260];
    __shared__ __align__(16) float s_u[C * 260];
    __shared__ float s_nc[C];
    __shared__ float s_cntf[C];
    __shared__ float s_pair[C * C];
    __shared__ float s_sim[C];
    const int tid = threadIdx.x;

    if (tid < C) {
        int t = 0;
        #pragma unroll
        for (int r = 0; r < 64; ++r) t += wsi[OFF_PCNT + r * 19 + tid];
        s_cntf[tid] = (float)t;
    }
    __syncthreads();
    for (int i = tid; i < C * 256; i += 512) {
        int c = i >> 8, d = i & 255;
        float icnt = 1.f / fmaxf(s_cntf[c], 1.f);
        s_cen[c * 260 + d] = (float)wsi[OFF_S + i] * IS_S * icnt;
        s_u[c * 260 + d]   = (float)wsi[OFF_U + i] * IS_U;
    }
    __syncthreads();
    if (tid < C) {
        float nsq = 0.f;
        for (int d = 0; d < D_DIM; ++d) {
            float x = s_cen[tid * 260 + d];
            nsq += x * x;
        }
        s_nc[tid] = sqrtf(nsq);
    }
    __syncthreads();
    if (tid < C * C) {
        int i = tid / C, j = tid % C;
        const float4* ci = (const float4*)&s_cen[i * 260];
        const float4* cj = (const float4*)&s_cen[j * 260];
        float dot = 0.f;
        #pragma unroll 8
        for (int k = 0; k < 64; ++k) {
            float4 a = ci[k], bb = cj[k];
            dot += a.x * bb.x + a.y * bb.y + a.z * bb.z + a.w * bb.w;
        }
        float S = dot / fmaxf(s_nc[i] * s_nc[j], EPS);
        s_pair[tid] = (i == j) ? (1.f - S) : fmaxf(S, 0.f);
    } else if (tid >= 384 && tid < 384 + C) {
        int i = tid - 384;
        const float4* ci = (const float4*)&s_cen[i * 260];
        const float4* ui = (const float4*)&s_u[i * 260];
        float dot = 0.f;
        #pragma unroll 8
        for (int k = 0; k < 64; ++k) {
            float4 a = ci[k], bb = ui[k];
            dot += a.x * bb.x + a.y * bb.y + a.z * bb.z + a.w * bb.w;
        }
        s_sim[i] = (s_cntf[i] > 0.f)
                 ? (1.f - dot / fmaxf(s_nc[i] * s_cntf[i], EPS)) : 0.f;
    }
    __syncthreads();
    if (tid < C) {
        float row = 0.f;
        for (int j = 0; j < C; ++j) row += s_pair[tid * C + j];
        s_pair[tid * C] = (s_cntf[tid] > 0.f) ? (row * (1.f / (float)C)) : 0.f;
    }
    __syncthreads();
    if (tid == 0) {
        float tot = 0.f;
        for (int i = 0; i < C; ++i) tot += s_pair[i * C] + s_sim[i];
        out[0] = tot;
    }
}

extern "C" void kernel_launch(void* const* d_in, const int* in_sizes, int n_in,
                              void* d_out, int out_size, void* d_ws, size_t ws_size,
                              hipStream_t stream) {
    const float* in  = (const float*)d_in[0];
    const int*   tgt = (const int*)d_in[1];
    float* out = (float*)d_out;
    int*   wsi = (int*)d_ws;

    kA_stream<<<2048, 256, 0, stream>>>(in, tgt, wsi);
    kA2_io<<<64, 256, 0, stream>>>(wsi);
    kB_stream<<<2048, 256, 0, stream>>>(in, tgt, wsi);
    kM_merge<<<64, 256, 0, stream>>>(wsi);
    k2_final<<<1, 512, 0, stream>>>(wsi, out);
}